// Round 1
// baseline (14572.922 us; speedup 1.0000x reference)
//
#include <hip/hip_runtime.h>
#include <hip/hip_bf16.h>

#define NBLK 50
#define HID  16
#define BATCH 16
#define HH 128
#define WW 128
#define CPAD 64      // padded channel count (real max 51)
#define PH 136       // 128 + 2*4 spatial zero pad
#define PW 136

typedef __attribute__((ext_vector_type(8))) short short8;    // 8 bf16 (A/B frag)
typedef __attribute__((ext_vector_type(4))) float floatx4;   // C/D frag

static __device__ __forceinline__ unsigned short f2bf(float f) {
    // round-to-nearest-even fp32 -> bf16 bits
    unsigned int u = __float_as_uint(f);
    unsigned int r = (u + 0x7fffu + ((u >> 16) & 1u)) >> 16;
    return (unsigned short)r;
}

// Pack w1 (fp32, [50][16][51][9][9]) -> wbuf bf16 [blk][tap][hc][c(0..63)]
// with zeros for c > blk (channels not yet produced when block blk runs —
// this makes the K-padding AND the concurrent-write channel read-safe).
__global__ void prep_w(const float* __restrict__ w1, unsigned short* __restrict__ wbuf) {
    int idx = blockIdx.x * 256 + threadIdx.x;
    const int total = NBLK * 81 * HID * CPAD;
    if (idx >= total) return;
    int c   = idx & (CPAD - 1);
    int hc  = (idx >> 6) & (HID - 1);
    int rest = idx >> 10;
    int tap = rest % 81;
    int blk = rest / 81;
    float v = 0.f;
    if (c <= blk) {  // valid input channels for this block: 0..blk
        v = w1[(((size_t)blk * HID + hc) * (1 + NBLK) + c) * 81 + tap];
    }
    wbuf[idx] = f2bf(v);
}

// Scatter x (fp32 [16][1][128][128]) into feats channel 0 (bf16, channels-last).
__global__ void init_x(const float* __restrict__ x, unsigned short* __restrict__ feats) {
    int idx = blockIdx.x * 256 + threadIdx.x;
    if (idx >= BATCH * HH * WW) return;
    int xw = idx & (WW - 1);
    int yy = (idx >> 7) & (HH - 1);
    int b  = idx >> 14;
    feats[(((size_t)b * PH + (yy + 4)) * PW + (xw + 4)) * CPAD] = f2bf(x[idx]);
}

// One dense block: conv(9x9, Cin=blk+1 -> 16) + bias + relu + <h,w2> + bias + sigmoid.
// Grid: one workgroup per (b, y) row = 2048 wg. 256 threads = 4 waves,
// wave handles 32 pixels (2 MFMA n-tiles). K = channels, taps looped.
__global__ __launch_bounds__(256) void block_kern(
    unsigned short* feats,                      // read chans 0..blk, write chan blk+1
    const unsigned short* __restrict__ wbuf,
    const float* __restrict__ bias1, const float* __restrict__ w2,
    const float* __restrict__ bias2, float* __restrict__ out,
    int blk, int nchunk)
{
    const int wg   = blockIdx.x;
    const int y    = wg & (HH - 1);
    const int b    = wg >> 7;
    const int lane = threadIdx.x & 63;
    const int wave = threadIdx.x >> 6;
    const int n    = lane & 15;   // pixel within 16-tile / hc row selector in A
    const int kg   = lane >> 4;   // k-group (8 channels each)
    const int x0   = wave * 32;

    floatx4 acc0 = {0.f, 0.f, 0.f, 0.f};
    floatx4 acc1 = {0.f, 0.f, 0.f, 0.f};

    // A-frag base: wbuf[blk][tap][m=n][k=kg*8+j], tap stride = HID*CPAD = 1024
    const unsigned short* wblk = wbuf + (size_t)blk * 81 * HID * CPAD + n * CPAD + kg * 8;
    const unsigned short* fb   = feats + (size_t)b * PH * PW * CPAD;

    for (int ky = 0; ky < 9; ++ky) {
        // padded input row = y + ky (unpadded y + ky - 4)
        const unsigned short* frow = fb + ((size_t)(y + ky) * PW + (x0 + n)) * CPAD + kg * 8;
        for (int ch = 0; ch < nchunk; ++ch) {
            const int c0 = ch * 32;
            const unsigned short* wt = wblk + (ky * 9) * (HID * CPAD) + c0;
            const unsigned short* fp = frow + c0;
            #pragma unroll
            for (int kx = 0; kx < 9; ++kx) {
                short8 af  = *(const short8*)(wt + kx * (HID * CPAD));
                short8 bf0 = *(const short8*)(fp + kx * CPAD);            // tile 0
                short8 bf1 = *(const short8*)(fp + (kx + 16) * CPAD);     // tile 1
                acc0 = __builtin_amdgcn_mfma_f32_16x16x32_bf16(af, bf0, acc0, 0, 0, 0);
                acc1 = __builtin_amdgcn_mfma_f32_16x16x32_bf16(af, bf1, acc1, 0, 0, 0);
            }
        }
    }

    // Epilogue. D layout: col(n)=lane&15 = pixel, row(m)=kg*4+r = hidden channel.
    float p0 = 0.f, p1 = 0.f;
    #pragma unroll
    for (int r = 0; r < 4; ++r) {
        int hc = kg * 4 + r;
        float bv = bias1[blk * HID + hc];
        float wv = w2[blk * HID + hc];
        float h0 = fmaxf(acc0[r] + bv, 0.f);
        float h1 = fmaxf(acc1[r] + bv, 0.f);
        p0 += h0 * wv;
        p1 += h1 * wv;
    }
    // sum the 16 hidden channels: 4 regs done above, now across the 4 kg lane-groups
    p0 += __shfl_xor(p0, 16, 64); p0 += __shfl_xor(p0, 32, 64);
    p1 += __shfl_xor(p1, 16, 64); p1 += __shfl_xor(p1, 32, 64);

    if (kg == 0) {
        float bb = bias2[blk];
        float y0 = 1.f / (1.f + __expf(-(p0 + bb)));
        float y1 = 1.f / (1.f + __expf(-(p1 + bb)));
        int px0 = x0 + n, px1 = x0 + 16 + n;
        size_t ob = (((size_t)b * NBLK + blk) * HH + y) * WW;
        out[ob + px0] = y0;
        out[ob + px1] = y1;
        unsigned short* fw = feats + (((size_t)b * PH + (y + 4)) * PW) * CPAD + (blk + 1);
        fw[(size_t)(px0 + 4) * CPAD] = f2bf(y0);
        fw[(size_t)(px1 + 4) * CPAD] = f2bf(y1);
    }
}

extern "C" void kernel_launch(void* const* d_in, const int* in_sizes, int n_in,
                              void* d_out, int out_size, void* d_ws, size_t ws_size,
                              hipStream_t stream) {
    const float* x  = (const float*)d_in[0];
    const float* w1 = (const float*)d_in[1];
    const float* b1 = (const float*)d_in[2];
    const float* w2 = (const float*)d_in[3];
    const float* b2 = (const float*)d_in[4];
    float* out = (float*)d_out;

    unsigned short* feats = (unsigned short*)d_ws;
    size_t feats_bytes = (size_t)BATCH * PH * PW * CPAD * sizeof(unsigned short); // ~37.9 MB
    unsigned short* wbuf = (unsigned short*)((char*)d_ws + feats_bytes);          // ~8.3 MB

    hipMemsetAsync(feats, 0, feats_bytes, stream);
    init_x<<<(BATCH * HH * WW + 255) / 256, 256, 0, stream>>>(x, feats);
    const int wtotal = NBLK * 81 * HID * CPAD;
    prep_w<<<(wtotal + 255) / 256, 256, 0, stream>>>(w1, wbuf);

    for (int blk = 0; blk < NBLK; ++blk) {
        int nchunk = (blk + 32) / 32;  // ceil((blk+1)/32)
        block_kern<<<BATCH * HH, 256, 0, stream>>>(feats, wbuf, b1, w2, b2, out, blk, nchunk);
    }
}

// Round 2
// 1674.851 us; speedup vs baseline: 8.7010x; 8.7010x over previous
//
#include <hip/hip_runtime.h>
#include <hip/hip_bf16.h>

#define NBLK 50
#define HID  16
#define BATCH 16
#define HH 128
#define WW 128
#define PH 136
#define PW 136
#define NCH 2
#define ROWCH (PW*32)   // 4352 elements per (row, chunk) = 8704 B
#define ROWPAD 4608     // padded LDS row (pad absorbs any tail overrun)
#define TAPE 512        // elements per A tap-fragment (64 lanes * 8)

typedef __attribute__((ext_vector_type(8))) short short8;
typedef __attribute__((ext_vector_type(4))) float floatx4;

static __device__ __forceinline__ unsigned short f2bf(float f) {
    unsigned int u = __float_as_uint(f);
    unsigned int r = (u + 0x7fffu + ((u >> 16) & 1u)) >> 16;
    return (unsigned short)r;
}

#define GLD16(gp, lp) __builtin_amdgcn_global_load_lds( \
    (__attribute__((address_space(1))) void*)(void*)(gp), \
    (__attribute__((address_space(3))) void*)(lp), 16, 0, 0)

// Stage one feats row-chunk (8704 B contiguous) into LDS.
static __device__ __forceinline__ void stage_row(const unsigned short* g, unsigned short* l, int tid) {
    const char* gb = (const char*)g;
    char* lb = (char*)l;
    GLD16(gb + tid * 16,        lb + (tid & ~63) * 16);
    GLD16(gb + 4096 + tid * 16, lb + 4096 + (tid & ~63) * 16);
    if (tid < 32) GLD16(gb + 8192 + tid * 16, lb + 8192 + (tid & ~63) * 16);
}

// Stage 9 A tap-fragments (9216 B contiguous) into LDS.
static __device__ __forceinline__ void stage_a(const unsigned short* g, unsigned short* l, int tid) {
    const char* gb = (const char*)g;
    char* lb = (char*)l;
    GLD16(gb + tid * 16,        lb + (tid & ~63) * 16);
    GLD16(gb + 4096 + tid * 16, lb + 4096 + (tid & ~63) * 16);
    if (tid < 64) GLD16(gb + 8192 + tid * 16, lb + 8192 + (tid & ~63) * 16);
}

// Pack w1 (fp32 [50][16][51][9][9]) into A-fragment order:
// wbuf[blk][chunk][tap][lane][8], lane: m=lane&15 (hidden ch), k=(lane>>4)*8+j.
// Zero for c>blk (K-padding + write-channel read-safety).
__global__ void prep_w(const float* __restrict__ w1, unsigned short* __restrict__ wbuf) {
    int idx = blockIdx.x * 256 + threadIdx.x;
    const int total = NBLK * NCH * 81 * TAPE;
    if (idx >= total) return;
    int e    = idx & 7;
    int lane = (idx >> 3) & 63;
    int tap  = (idx >> 9) % 81;
    int bc   = idx / (81 * TAPE);
    int ch   = bc & 1, blk = bc >> 1;
    int hc   = lane & 15;
    int c    = ch * 32 + (lane >> 4) * 8 + e;
    float v = 0.f;
    if (c <= blk) v = w1[(((size_t)blk * HID + hc) * (1 + NBLK) + c) * 81 + tap];
    wbuf[idx] = f2bf(v);
}

// Scatter x into feats channel 0, chunk 0 (chunk-split channels-last layout).
__global__ void init_x(const float* __restrict__ x, unsigned short* __restrict__ feats) {
    int idx = blockIdx.x * 256 + threadIdx.x;
    if (idx >= BATCH * HH * WW) return;
    int xw = idx & (WW - 1);
    int yy = (idx >> 7) & (HH - 1);
    int b  = idx >> 14;
    feats[(((size_t)b * PH + (yy + 4)) * NCH) * ROWCH + (size_t)(xw + 4) * 32] = f2bf(x[idx]);
}

// One dense block. wg = (b, 4-row strip), 4 waves x 32 px. Per step r the
// staged input row r serves all (o,ky) with o+ky==r: 4x B-frag reuse, A held
// in a 4-deep ky register window.
__global__ __launch_bounds__(256, 2) void block_kern(
    unsigned short* feats, const unsigned short* __restrict__ wbuf,
    const float* __restrict__ b1, const float* __restrict__ w2,
    const float* __restrict__ b2, float* __restrict__ out,
    int blk, int nchunk)
{
    __shared__ __align__(16) unsigned short sB[2][ROWPAD];
    __shared__ __align__(16) unsigned short sA[2][9 * TAPE];

    const int s    = blockIdx.x & 31;
    const int b    = blockIdx.x >> 5;
    const int tid  = threadIdx.x;
    const int lane = tid & 63;
    const int wv   = tid >> 6;
    const int n    = lane & 15;
    const int kg   = lane >> 4;
    const int x0   = wv * 32;

    floatx4 acc[4][2];
    #pragma unroll
    for (int o = 0; o < 4; ++o)
        #pragma unroll
        for (int t = 0; t < 2; ++t)
            acc[o][t] = (floatx4){0.f, 0.f, 0.f, 0.f};

    const unsigned short* fb = feats + (size_t)b * PH * NCH * ROWCH;

    for (int c = 0; c < nchunk; ++c) {
        const unsigned short* wsrc = wbuf + (size_t)(blk * NCH + c) * 81 * TAPE;
        stage_row(fb + (size_t)((4 * s) * NCH + c) * ROWCH, &sB[0][0], tid);
        stage_a(wsrc, &sA[0][0], tid);
        __syncthreads();

        short8 Areg[4][9];
        #pragma unroll
        for (int step = 0; step < 12; ++step) {
            if (step < 11)
                stage_row(fb + (size_t)((4 * s + step + 1) * NCH + c) * ROWCH,
                          &sB[(step + 1) & 1][0], tid);
            if (step < 8)
                stage_a(wsrc + (size_t)(step + 1) * 9 * TAPE, &sA[(step + 1) & 1][0], tid);

            if (step <= 8) {
                const unsigned short* ab = &sA[step & 1][0];
                #pragma unroll
                for (int kx = 0; kx < 9; ++kx)
                    Areg[step & 3][kx] = *(const short8*)(ab + kx * TAPE + lane * 8);
            }

            const unsigned short* bb = &sB[step & 1][0];
            #pragma unroll
            for (int kx = 0; kx < 9; ++kx) {
                short8 B0 = *(const short8*)(bb + (x0 + kx + n) * 32 + kg * 8);
                short8 B1 = *(const short8*)(bb + (x0 + 16 + kx + n) * 32 + kg * 8);
                #pragma unroll
                for (int o = 0; o < 4; ++o) {
                    if (o <= step && step - o <= 8) {
                        acc[o][0] = __builtin_amdgcn_mfma_f32_16x16x32_bf16(
                            Areg[(step - o) & 3][kx], B0, acc[o][0], 0, 0, 0);
                        acc[o][1] = __builtin_amdgcn_mfma_f32_16x16x32_bf16(
                            Areg[(step - o) & 3][kx], B1, acc[o][1], 0, 0, 0);
                    }
                }
            }
            __syncthreads();
        }
    }

    // Epilogue: relu(h+b1)·w2, reduce 16 hidden (4 regs + kg xor-shuffles),
    // sigmoid, write out + feats channel blk+1.
    float b1v[4], w2v[4];
    #pragma unroll
    for (int r = 0; r < 4; ++r) {
        b1v[r] = b1[blk * HID + kg * 4 + r];
        w2v[r] = w2[blk * HID + kg * 4 + r];
    }
    const float bb2 = b2[blk];
    const int cw = blk + 1, cchunk = cw >> 5, cidx = cw & 31;

    #pragma unroll
    for (int o = 0; o < 4; ++o) {
        const int yrow = 4 * s + o;
        #pragma unroll
        for (int t = 0; t < 2; ++t) {
            float p = 0.f;
            #pragma unroll
            for (int r = 0; r < 4; ++r)
                p += fmaxf(acc[o][t][r] + b1v[r], 0.f) * w2v[r];
            p += __shfl_xor(p, 16, 64);
            p += __shfl_xor(p, 32, 64);
            if (kg == 0) {
                float yv = 1.f / (1.f + __expf(-(p + bb2)));
                int px = x0 + 16 * t + n;
                out[(((size_t)b * NBLK + blk) * HH + yrow) * WW + px] = yv;
                feats[(((size_t)b * PH + (yrow + 4)) * NCH + cchunk) * ROWCH
                      + (size_t)(px + 4) * 32 + cidx] = f2bf(yv);
            }
        }
    }
}

extern "C" void kernel_launch(void* const* d_in, const int* in_sizes, int n_in,
                              void* d_out, int out_size, void* d_ws, size_t ws_size,
                              hipStream_t stream) {
    const float* x  = (const float*)d_in[0];
    const float* w1 = (const float*)d_in[1];
    const float* b1 = (const float*)d_in[2];
    const float* w2 = (const float*)d_in[3];
    const float* b2 = (const float*)d_in[4];
    float* out = (float*)d_out;

    unsigned short* feats = (unsigned short*)d_ws;
    size_t feats_bytes = (size_t)BATCH * PH * NCH * ROWCH * sizeof(unsigned short); // ~37.9 MB
    unsigned short* wbuf = (unsigned short*)((char*)d_ws + feats_bytes);            // ~8.3 MB

    hipMemsetAsync(feats, 0, feats_bytes, stream);
    init_x<<<(BATCH * HH * WW + 255) / 256, 256, 0, stream>>>(x, feats);
    const int wtotal = NBLK * NCH * 81 * TAPE;
    prep_w<<<(wtotal + 255) / 256, 256, 0, stream>>>(w1, wbuf);

    for (int blk = 0; blk < NBLK; ++blk) {
        int nchunk = (blk + 32) / 32;  // ceil((blk+1)/32)
        block_kern<<<BATCH * 32, 256, 0, stream>>>(feats, wbuf, b1, w2, b2, out, blk, nchunk);
    }
}

// Round 3
// 1584.311 us; speedup vs baseline: 9.1983x; 1.0571x over previous
//
#include <hip/hip_runtime.h>
#include <hip/hip_bf16.h>

#define NBLK 50
#define HID  16
#define BATCH 16
#define HH 128
#define WW 128
#define PH 136
#define PW 136
#define NCH 2
#define PXS 40                 // shorts per pixel (80 B stride: bank-conflict-free)
#define ROWE (PW*PXS)          // 5440 shorts = 10880 B per (row, chunk)
#define SBE  5504              // LDS row buffer (pad to 11008 B)
#define TAPE 512               // elements per A tap-fragment (64 lanes * 8)

typedef __attribute__((ext_vector_type(8))) short short8;
typedef __attribute__((ext_vector_type(4))) float floatx4;

static __device__ __forceinline__ unsigned short f2bf(float f) {
    unsigned int u = __float_as_uint(f);
    unsigned int r = (u + 0x7fffu + ((u >> 16) & 1u)) >> 16;
    return (unsigned short)r;
}

#define GLD16(gp, lp) __builtin_amdgcn_global_load_lds( \
    (__attribute__((address_space(1))) void*)(void*)(gp), \
    (__attribute__((address_space(3))) void*)(lp), 16, 0, 0)

// Stage one feats row-chunk (10880 B contiguous) into LDS.
static __device__ __forceinline__ void stage_row(const unsigned short* g, unsigned short* l, int tid) {
    const char* gb = (const char*)g;
    char* lb = (char*)l;
    GLD16(gb + tid * 16,        lb + (tid & ~63) * 16);
    GLD16(gb + 4096 + tid * 16, lb + 4096 + (tid & ~63) * 16);
    if (tid < 168) GLD16(gb + 8192 + tid * 16, lb + 8192 + (tid & ~63) * 16);
}

// Stage 9 A tap-fragments (9216 B contiguous) into LDS.
static __device__ __forceinline__ void stage_a(const unsigned short* g, unsigned short* l, int tid) {
    const char* gb = (const char*)g;
    char* lb = (char*)l;
    GLD16(gb + tid * 16,        lb + (tid & ~63) * 16);
    GLD16(gb + 4096 + tid * 16, lb + 4096 + (tid & ~63) * 16);
    if (tid < 64) GLD16(gb + 8192 + tid * 16, lb + 8192 + (tid & ~63) * 16);
}

// Pack w1 (fp32 [50][16][51][9][9]) into A-fragment order:
// wbuf[blk][chunk][tap][lane][8], lane: m=lane&15 (hidden ch), k=(lane>>4)*8+j.
// Zero for c>blk (K-padding + write-channel read-safety).
__global__ void prep_w(const float* __restrict__ w1, unsigned short* __restrict__ wbuf) {
    int idx = blockIdx.x * 256 + threadIdx.x;
    const int total = NBLK * NCH * 81 * TAPE;
    if (idx >= total) return;
    int e    = idx & 7;
    int lane = (idx >> 3) & 63;
    int tap  = (idx >> 9) % 81;
    int bc   = idx / (81 * TAPE);
    int ch   = bc & 1, blk = bc >> 1;
    int hc   = lane & 15;
    int c    = ch * 32 + (lane >> 4) * 8 + e;
    float v = 0.f;
    if (c <= blk) v = w1[(((size_t)blk * HID + hc) * (1 + NBLK) + c) * 81 + tap];
    wbuf[idx] = f2bf(v);
}

// Zero only the halo pixels (spatial pad). Unwritten interior channels are
// safe: their weight columns are zeroed in wbuf, and 0xAA-poison bf16 is
// finite, so 0*garbage contributes exactly 0.
__global__ void zero_halo(unsigned short* __restrict__ feats) {
    int t = blockIdx.x * 256 + threadIdx.x;
    const int PPX = 2112;                 // halo px per (b, chunk)
    const int TOT = BATCH * NCH * PPX * 5;
    if (t >= TOT) return;
    int w    = t % 5;
    int rest = t / 5;
    int p    = rest % PPX;
    int ch   = (rest / PPX) % NCH;
    int b    = rest / (PPX * NCH);
    int row, px;
    if (p < 1088) {                        // rows 0-3, 132-135 (full)
        int r4 = p / 136; px = p % 136;
        row = (r4 < 4) ? r4 : r4 + 128;
    } else {                               // rows 4-131, cols 0-3 & 132-135
        int q = p - 1088;
        row = 4 + (q >> 3);
        int c = q & 7;
        px = (c < 4) ? c : c + 128;
    }
    float4* dst = (float4*)((char*)feats +
        (((((size_t)b * PH + row) * NCH + ch) * ROWE + (size_t)px * PXS) * 2) + (size_t)w * 16);
    *dst = make_float4(0.f, 0.f, 0.f, 0.f);
}

// Scatter x into feats channel 0, chunk 0.
__global__ void init_x(const float* __restrict__ x, unsigned short* __restrict__ feats) {
    int idx = blockIdx.x * 256 + threadIdx.x;
    if (idx >= BATCH * HH * WW) return;
    int xw = idx & (WW - 1);
    int yy = (idx >> 7) & (HH - 1);
    int b  = idx >> 14;
    feats[(((size_t)b * PH + (yy + 4)) * NCH) * ROWE + (size_t)(xw + 4) * PXS] = f2bf(x[idx]);
}

// One dense block. wg = (b, 4-row strip), 4 waves x 32 px. Per step r the
// staged input row r serves all (o,ky) with o+ky==r: 4x B-frag reuse, A held
// in a 4-deep ky register window. 80-B pixel stride => conflict-free ds_read.
__global__ __launch_bounds__(256, 2) void block_kern(
    unsigned short* feats, const unsigned short* __restrict__ wbuf,
    const float* __restrict__ b1, const float* __restrict__ w2,
    const float* __restrict__ b2, float* __restrict__ out,
    int blk, int nchunk)
{
    __shared__ __align__(16) unsigned short sB[2][SBE];
    __shared__ __align__(16) unsigned short sA[2][9 * TAPE];

    const int s    = blockIdx.x & 31;
    const int b    = blockIdx.x >> 5;
    const int tid  = threadIdx.x;
    const int lane = tid & 63;
    const int wv   = tid >> 6;
    const int n    = lane & 15;
    const int kg   = lane >> 4;
    const int x0   = wv * 32;

    floatx4 acc[4][2];
    #pragma unroll
    for (int o = 0; o < 4; ++o)
        #pragma unroll
        for (int t = 0; t < 2; ++t)
            acc[o][t] = (floatx4){0.f, 0.f, 0.f, 0.f};

    const unsigned short* fb = feats + (size_t)b * PH * NCH * ROWE;

    for (int c = 0; c < nchunk; ++c) {
        const unsigned short* wsrc = wbuf + (size_t)(blk * NCH + c) * 81 * TAPE;
        stage_row(fb + (size_t)((4 * s) * NCH + c) * ROWE, &sB[0][0], tid);
        stage_a(wsrc, &sA[0][0], tid);
        __syncthreads();

        short8 Areg[4][9];
        #pragma unroll
        for (int step = 0; step < 12; ++step) {
            if (step < 11)
                stage_row(fb + (size_t)((4 * s + step + 1) * NCH + c) * ROWE,
                          &sB[(step + 1) & 1][0], tid);
            if (step < 8)
                stage_a(wsrc + (size_t)(step + 1) * 9 * TAPE, &sA[(step + 1) & 1][0], tid);

            if (step <= 8) {
                const unsigned short* ab = &sA[step & 1][0];
                #pragma unroll
                for (int kx = 0; kx < 9; ++kx)
                    Areg[step & 3][kx] = *(const short8*)(ab + kx * TAPE + lane * 8);
            }

            const unsigned short* bb = &sB[step & 1][0];
            #pragma unroll
            for (int kx = 0; kx < 9; ++kx) {
                short8 B0 = *(const short8*)(bb + (x0 + kx + n) * PXS + kg * 8);
                short8 B1 = *(const short8*)(bb + (x0 + 16 + kx + n) * PXS + kg * 8);
                #pragma unroll
                for (int o = 0; o < 4; ++o) {
                    if (o <= step && step - o <= 8) {
                        acc[o][0] = __builtin_amdgcn_mfma_f32_16x16x32_bf16(
                            Areg[(step - o) & 3][kx], B0, acc[o][0], 0, 0, 0);
                        acc[o][1] = __builtin_amdgcn_mfma_f32_16x16x32_bf16(
                            Areg[(step - o) & 3][kx], B1, acc[o][1], 0, 0, 0);
                    }
                }
            }
            __syncthreads();
        }
    }

    // Epilogue: relu(h+b1)·w2, reduce 16 hidden, sigmoid, write out + feats.
    float b1v[4], w2v[4];
    #pragma unroll
    for (int r = 0; r < 4; ++r) {
        b1v[r] = b1[blk * HID + kg * 4 + r];
        w2v[r] = w2[blk * HID + kg * 4 + r];
    }
    const float bb2 = b2[blk];
    const int cw = blk + 1, cchunk = cw >> 5, cidx = cw & 31;

    #pragma unroll
    for (int o = 0; o < 4; ++o) {
        const int yrow = 4 * s + o;
        #pragma unroll
        for (int t = 0; t < 2; ++t) {
            float p = 0.f;
            #pragma unroll
            for (int r = 0; r < 4; ++r)
                p += fmaxf(acc[o][t][r] + b1v[r], 0.f) * w2v[r];
            p += __shfl_xor(p, 16, 64);
            p += __shfl_xor(p, 32, 64);
            if (kg == 0) {
                float yv = 1.f / (1.f + __expf(-(p + bb2)));
                int px = x0 + 16 * t + n;
                out[(((size_t)b * NBLK + blk) * HH + yrow) * WW + px] = yv;
                feats[(((size_t)b * PH + (yrow + 4)) * NCH + cchunk) * ROWE
                      + (size_t)(px + 4) * PXS + cidx] = f2bf(yv);
            }
        }
    }
}

extern "C" void kernel_launch(void* const* d_in, const int* in_sizes, int n_in,
                              void* d_out, int out_size, void* d_ws, size_t ws_size,
                              hipStream_t stream) {
    const float* x  = (const float*)d_in[0];
    const float* w1 = (const float*)d_in[1];
    const float* b1 = (const float*)d_in[2];
    const float* w2 = (const float*)d_in[3];
    const float* b2 = (const float*)d_in[4];
    float* out = (float*)d_out;

    unsigned short* feats = (unsigned short*)d_ws;
    size_t feats_bytes = (size_t)BATCH * PH * NCH * ROWE * sizeof(unsigned short); // ~47.3 MB
    unsigned short* wbuf = (unsigned short*)((char*)d_ws + feats_bytes);           // ~8.3 MB

    const int htotal = BATCH * NCH * 2112 * 5;
    zero_halo<<<(htotal + 255) / 256, 256, 0, stream>>>(feats);
    init_x<<<(BATCH * HH * WW + 255) / 256, 256, 0, stream>>>(x, feats);
    const int wtotal = NBLK * NCH * 81 * TAPE;
    prep_w<<<(wtotal + 255) / 256, 256, 0, stream>>>(w1, wbuf);

    for (int blk = 0; blk < NBLK; ++blk) {
        int nchunk = (blk + 32) / 32;  // ceil((blk+1)/32)
        block_kern<<<BATCH * 32, 256, 0, stream>>>(feats, wbuf, b1, w2, b2, out, blk, nchunk);
    }
}

// Round 4
// 1576.816 us; speedup vs baseline: 9.2420x; 1.0048x over previous
//
#include <hip/hip_runtime.h>
#include <hip/hip_bf16.h>

#define NBLK 50
#define HID  16
#define BATCH 16
#define HH 128
#define WW 128
#define PH 136
#define PW 136
#define NCH 2
#define PXS 32                 // shorts per pixel (64 B)
#define ROWE (PW*PXS)          // 4352 shorts = 8704 B per (row, chunk)
#define TAPE 512               // elements per A tap-fragment (64 lanes * 8)

typedef __attribute__((ext_vector_type(8))) short short8;
typedef __attribute__((ext_vector_type(4))) float floatx4;

static __device__ __forceinline__ unsigned short f2bf(float f) {
    unsigned int u = __float_as_uint(f);
    unsigned int r = (u + 0x7fffu + ((u >> 16) & 1u)) >> 16;
    return (unsigned short)r;
}

#define GLD16(gp, lp) __builtin_amdgcn_global_load_lds( \
    (__attribute__((address_space(1))) void*)(void*)(gp), \
    (__attribute__((address_space(3))) void*)(lp), 16, 0, 0)

// Stage one feats row-chunk (8704 B contiguous) into LDS.
static __device__ __forceinline__ void stage_row(const unsigned short* g, unsigned short* l, int tid) {
    const char* gb = (const char*)g;
    char* lb = (char*)l;
    GLD16(gb + tid * 16,        lb + (tid & ~63) * 16);
    GLD16(gb + 4096 + tid * 16, lb + 4096 + (tid & ~63) * 16);
    if (tid < 32) GLD16(gb + 8192 + tid * 16, lb + 8192 + (tid & ~63) * 16);
}

// Pack w1 (fp32 [50][16][51][9][9]) into A-fragment order:
// wbuf[blk][chunk][tap][lane][8], lane: m=lane&15 (hidden ch), k=(lane>>4)*8+j.
// Zero for c>blk (K-padding + write-channel read-safety).
__global__ void prep_w(const float* __restrict__ w1, unsigned short* __restrict__ wbuf) {
    int idx = blockIdx.x * 256 + threadIdx.x;
    const int total = NBLK * NCH * 81 * TAPE;
    if (idx >= total) return;
    int e    = idx & 7;
    int lane = (idx >> 3) & 63;
    int tap  = (idx >> 9) % 81;
    int bc   = idx / (81 * TAPE);
    int ch   = bc & 1, blk = bc >> 1;
    int hc   = lane & 15;
    int c    = ch * 32 + (lane >> 4) * 8 + e;
    float v = 0.f;
    if (c <= blk) v = w1[(((size_t)blk * HID + hc) * (1 + NBLK) + c) * 81 + tap];
    wbuf[idx] = f2bf(v);
}

// Zero only the halo pixels. Unwritten interior channels are safe: their
// weight columns are zeroed in wbuf, and 0xAA-poison bf16 is finite.
__global__ void zero_halo(unsigned short* __restrict__ feats) {
    int t = blockIdx.x * 256 + threadIdx.x;
    const int PPX = 2112;                 // halo px per (b, chunk)
    const int TOT = BATCH * NCH * PPX * 4;
    if (t >= TOT) return;
    int w    = t & 3;
    int rest = t >> 2;
    int p    = rest % PPX;
    int ch   = (rest / PPX) % NCH;
    int b    = rest / (PPX * NCH);
    int row, px;
    if (p < 1088) {                        // rows 0-3, 132-135 (full)
        int r4 = p / 136; px = p % 136;
        row = (r4 < 4) ? r4 : r4 + 128;
    } else {                               // rows 4-131, cols 0-3 & 132-135
        int q = p - 1088;
        row = 4 + (q >> 3);
        int c = q & 7;
        px = (c < 4) ? c : c + 128;
    }
    float4* dst = (float4*)((char*)feats +
        (((((size_t)b * PH + row) * NCH + ch) * ROWE + (size_t)px * PXS) * 2) + (size_t)w * 16);
    *dst = make_float4(0.f, 0.f, 0.f, 0.f);
}

// Scatter x into feats channel 0, chunk 0.
__global__ void init_x(const float* __restrict__ x, unsigned short* __restrict__ feats) {
    int idx = blockIdx.x * 256 + threadIdx.x;
    if (idx >= BATCH * HH * WW) return;
    int xw = idx & (WW - 1);
    int yy = (idx >> 7) & (HH - 1);
    int b  = idx >> 14;
    feats[(((size_t)b * PH + (yy + 4)) * NCH) * ROWE + (size_t)(xw + 4) * PXS] = f2bf(x[idx]);
}

// One dense block. wg = (b, 4-row strip), 4 waves x 32 px. Per step r the
// staged input row r serves all (o,ky) with o+ky==r: 4x B-frag reuse.
// A (weights) comes straight from global into a 4-deep ky register window
// (coalesced dwordx4, L2-resident) — LDS carries only B rows.
__global__ __launch_bounds__(256, 2) void block_kern(
    unsigned short* feats, const unsigned short* __restrict__ wbuf,
    const float* __restrict__ b1, const float* __restrict__ w2,
    const float* __restrict__ b2, float* __restrict__ out,
    int blk, int nchunk)
{
    __shared__ __align__(16) unsigned short sB[2][ROWE];

    const int s    = blockIdx.x & 31;
    const int b    = blockIdx.x >> 5;
    const int tid  = threadIdx.x;
    const int lane = tid & 63;
    const int wv   = tid >> 6;
    const int n    = lane & 15;
    const int kg   = lane >> 4;
    const int x0   = wv * 32;

    floatx4 acc[4][2];
    #pragma unroll
    for (int o = 0; o < 4; ++o)
        #pragma unroll
        for (int t = 0; t < 2; ++t)
            acc[o][t] = (floatx4){0.f, 0.f, 0.f, 0.f};

    const unsigned short* fb = feats + (size_t)b * PH * NCH * ROWE;

    for (int c = 0; c < nchunk; ++c) {
        const unsigned short* wsrc = wbuf + (size_t)(blk * NCH + c) * 81 * TAPE + lane * 8;

        short8 Areg[4][9];
        // prologue: stage row 0, load ky=0 taps into the window
        stage_row(fb + (size_t)((4 * s) * NCH + c) * ROWE, &sB[0][0], tid);
        #pragma unroll
        for (int kx = 0; kx < 9; ++kx)
            Areg[0][kx] = *(const short8*)(wsrc + (size_t)kx * TAPE);
        __syncthreads();

        #pragma unroll
        for (int step = 0; step < 12; ++step) {
            if (step < 11)
                stage_row(fb + (size_t)((4 * s + step + 1) * NCH + c) * ROWE,
                          &sB[(step + 1) & 1][0], tid);

            const unsigned short* bb = &sB[step & 1][0];
            #pragma unroll
            for (int kx = 0; kx < 9; ++kx) {
                short8 B0 = *(const short8*)(bb + (x0 + kx + n) * PXS + kg * 8);
                short8 B1 = *(const short8*)(bb + (x0 + 16 + kx + n) * PXS + kg * 8);
                #pragma unroll
                for (int o = 0; o < 4; ++o) {
                    if (o <= step && step - o <= 8) {
                        acc[o][0] = __builtin_amdgcn_mfma_f32_16x16x32_bf16(
                            Areg[(step - o) & 3][kx], B0, acc[o][0], 0, 0, 0);
                        acc[o][1] = __builtin_amdgcn_mfma_f32_16x16x32_bf16(
                            Areg[(step - o) & 3][kx], B1, acc[o][1], 0, 0, 0);
                    }
                }
            }

            // prefetch next ky's taps into the retiring window slot
            if (step < 8) {
                #pragma unroll
                for (int kx = 0; kx < 9; ++kx)
                    Areg[(step + 1) & 3][kx] =
                        *(const short8*)(wsrc + (size_t)((step + 1) * 9 + kx) * TAPE);
            }
            __syncthreads();
        }
    }

    // Epilogue: relu(h+b1)·w2, reduce 16 hidden, sigmoid, write out + feats.
    float b1v[4], w2v[4];
    #pragma unroll
    for (int r = 0; r < 4; ++r) {
        b1v[r] = b1[blk * HID + kg * 4 + r];
        w2v[r] = w2[blk * HID + kg * 4 + r];
    }
    const float bb2 = b2[blk];
    const int cw = blk + 1, cchunk = cw >> 5, cidx = cw & 31;

    #pragma unroll
    for (int o = 0; o < 4; ++o) {
        const int yrow = 4 * s + o;
        #pragma unroll
        for (int t = 0; t < 2; ++t) {
            float p = 0.f;
            #pragma unroll
            for (int r = 0; r < 4; ++r)
                p += fmaxf(acc[o][t][r] + b1v[r], 0.f) * w2v[r];
            p += __shfl_xor(p, 16, 64);
            p += __shfl_xor(p, 32, 64);
            if (kg == 0) {
                float yv = 1.f / (1.f + __expf(-(p + bb2)));
                int px = x0 + 16 * t + n;
                out[(((size_t)b * NBLK + blk) * HH + yrow) * WW + px] = yv;
                feats[(((size_t)b * PH + (yrow + 4)) * NCH + cchunk) * ROWE
                      + (size_t)(px + 4) * PXS + cidx] = f2bf(yv);
            }
        }
    }
}

extern "C" void kernel_launch(void* const* d_in, const int* in_sizes, int n_in,
                              void* d_out, int out_size, void* d_ws, size_t ws_size,
                              hipStream_t stream) {
    const float* x  = (const float*)d_in[0];
    const float* w1 = (const float*)d_in[1];
    const float* b1 = (const float*)d_in[2];
    const float* w2 = (const float*)d_in[3];
    const float* b2 = (const float*)d_in[4];
    float* out = (float*)d_out;

    unsigned short* feats = (unsigned short*)d_ws;
    size_t feats_bytes = (size_t)BATCH * PH * NCH * ROWE * sizeof(unsigned short); // ~37.9 MB
    unsigned short* wbuf = (unsigned short*)((char*)d_ws + feats_bytes);           // ~8.3 MB

    const int htotal = BATCH * NCH * 2112 * 4;
    zero_halo<<<(htotal + 255) / 256, 256, 0, stream>>>(feats);
    init_x<<<(BATCH * HH * WW + 255) / 256, 256, 0, stream>>>(x, feats);
    const int wtotal = NBLK * NCH * 81 * TAPE;
    prep_w<<<(wtotal + 255) / 256, 256, 0, stream>>>(w1, wbuf);

    for (int blk = 0; blk < NBLK; ++blk) {
        int nchunk = (blk + 32) / 32;  // ceil((blk+1)/32)
        block_kern<<<BATCH * 32, 256, 0, stream>>>(feats, wbuf, b1, w2, b2, out, blk, nchunk);
    }
}